// Round 5
// baseline (932.853 us; speedup 1.0000x reference)
//
#include <hip/hip_runtime.h>
#include <hip/hip_bf16.h>
#include <stdint.h>

#define NTOK  8192
#define HID   1024
#define INTER 4096
#define NEXP  8
#define NSLOT (NTOK * 2)

typedef __attribute__((ext_vector_type(4))) float f32x4;
typedef __attribute__((ext_vector_type(8))) short bf16x8;
typedef __attribute__((ext_vector_type(4))) short bf16x4;

__device__ __forceinline__ short f2bf(float f) {
  union { float f; uint32_t u; } v; v.f = f;
  uint32_t u = v.u;
  u += 0x7FFFu + ((u >> 16) & 1u);   // RNE
  return (short)(u >> 16);
}

// async global->LDS, 16B per lane; HW dest = wave-uniform base + lane*16
__device__ __forceinline__ void glds16(const short* g, short* l) {
  __builtin_amdgcn_global_load_lds(
      (const __attribute__((address_space(1))) void*)g,
      (__attribute__((address_space(3))) void*)l, 16, 0, 0);
}

// ---------------- cast x: fp32 -> bf16 --------------------------------------
__global__ __launch_bounds__(256) void castx_k(const float* __restrict__ in,
                                               short* __restrict__ out) {
  size_t i = ((size_t)blockIdx.x * 256 + threadIdx.x) * 4;
  f32x4 v = *(const f32x4*)(in + i);
  bf16x4 o = { f2bf(v.x), f2bf(v.y), f2bf(v.z), f2bf(v.w) };
  *(bf16x4*)(out + i) = o;
}

// ---------------- router: 16 tokens/block, block-reduced atomics ------------
__global__ __launch_bounds__(256) void router_k(
    const float* __restrict__ x, const float* __restrict__ rw,
    int* __restrict__ top_idx, float* __restrict__ top_w,
    float* __restrict__ probsum, float* __restrict__ cnt1) {
  __shared__ float lrw[NEXP * HID];       // 32 KB
  __shared__ float red[4][2 * NEXP];      // per-wave partials
  int tid = threadIdx.x;
  for (int i = tid * 4; i < NEXP * HID; i += 1024)
    *(f32x4*)(lrw + i) = *(const f32x4*)(rw + i);
  __syncthreads();
  int lane = tid & 63;
  int wv = tid >> 6;
  float pacc[NEXP], cacc[NEXP];
#pragma unroll
  for (int e = 0; e < NEXP; e++) { pacc[e] = 0.f; cacc[e] = 0.f; }
#pragma unroll
  for (int it = 0; it < 4; it++) {
    int t = blockIdx.x * 16 + it * 4 + wv;
    const float* xr = x + (size_t)t * HID;
    float acc[NEXP];
#pragma unroll
    for (int e = 0; e < NEXP; e++) acc[e] = 0.f;
#pragma unroll
    for (int k4 = 0; k4 < 4; k4++) {
      int k = k4 * 256 + lane * 4;
      f32x4 xv = *(const f32x4*)(xr + k);
#pragma unroll
      for (int e = 0; e < NEXP; e++) {
        f32x4 rv = *(const f32x4*)(lrw + e * HID + k);
        acc[e] += xv.x * rv.x + xv.y * rv.y + xv.z * rv.z + xv.w * rv.w;
      }
    }
#pragma unroll
    for (int e = 0; e < NEXP; e++) {
#pragma unroll
      for (int off = 32; off > 0; off >>= 1)
        acc[e] += __shfl_xor(acc[e], off);
    }
    float mx = acc[0];
#pragma unroll
    for (int e = 1; e < NEXP; e++) mx = fmaxf(mx, acc[e]);
    float p[NEXP], s = 0.f;
#pragma unroll
    for (int e = 0; e < NEXP; e++) { p[e] = expf(acc[e] - mx); s += p[e]; }
    float inv = 1.f / s;
    float p1 = -1.f, p2 = -1.f; int i1 = 0, i2 = 0;
#pragma unroll
    for (int e = 0; e < NEXP; e++) {
      float pe = p[e] * inv;
      p[e] = pe;
      if (pe > p1)      { p2 = p1; i2 = i1; p1 = pe; i1 = e; }
      else if (pe > p2) { p2 = pe; i2 = e; }
    }
    if (lane == 0) {
      float rs = 1.f / (p1 + p2);
      top_idx[t * 2] = i1; top_idx[t * 2 + 1] = i2;
      top_w[t * 2] = p1 * rs; top_w[t * 2 + 1] = p2 * rs;
#pragma unroll
      for (int e = 0; e < NEXP; e++) {
        pacc[e] += p[e];
        cacc[e] += (i1 == e) ? 1.f : 0.f;
      }
    }
  }
  if (lane == 0) {
#pragma unroll
    for (int e = 0; e < NEXP; e++) {
      red[wv][e] = pacc[e];
      red[wv][NEXP + e] = cacc[e];
    }
  }
  __syncthreads();
  if (tid < NEXP) {
    float s = 0.f, c = 0.f;
#pragma unroll
    for (int w = 0; w < 4; w++) { s += red[w][tid]; c += red[w][NEXP + tid]; }
    atomicAdd(&probsum[tid], s);
    atomicAdd(&cnt1[tid], c);
  }
}

__global__ void aux_k(const float* probsum, const float* cnt1, float* out_aux) {
  if (threadIdx.x == 0 && blockIdx.x == 0) {
    float s = 0.f;
    for (int e = 0; e < NEXP; e++) s += cnt1[e] * probsum[e];
    out_aux[0] = s * (float)NEXP / ((float)NTOK * (float)NTOK);
  }
}

__global__ void lists_k(const int* __restrict__ top_idx, int* __restrict__ cnt,
                        int* __restrict__ lists) {
  int i = blockIdx.x * 256 + threadIdx.x;
  if (i < NSLOT) {
    int e = top_idx[i];
    int pos = atomicAdd(cnt + e, 1);
    lists[e * NTOK + pos] = i;   // slot id = token*2 + k
  }
}

// -------- transpose + downcast: fp32 [K][N] -> bf16 [N][K], per expert ------
__global__ __launch_bounds__(256) void transpose_k(
    const float* __restrict__ in, short* __restrict__ out, int K, int N) {
  __shared__ short tile[64][72];   // +8 pad
  int e = blockIdx.z;
  in  += (size_t)e * K * N;
  out += (size_t)e * K * N;
  int n0 = blockIdx.x * 64, k0 = blockIdx.y * 64;
  int tid = threadIdx.x;
#pragma unroll
  for (int i = 0; i < 4; i++) {
    int k = (tid >> 4) + i * 16;
    int c = (tid & 15) * 4;
    f32x4 v = *(const f32x4*)(in + (size_t)(k0 + k) * N + n0 + c);
    tile[k][c] = f2bf(v.x); tile[k][c + 1] = f2bf(v.y);
    tile[k][c + 2] = f2bf(v.z); tile[k][c + 3] = f2bf(v.w);
  }
  __syncthreads();
#pragma unroll
  for (int i = 0; i < 2; i++) {
    int cid = tid + i * 256;
    int n = cid >> 3, kk = (cid & 7) * 8;
    bf16x8 o;
#pragma unroll
    for (int j = 0; j < 8; j++) o[j] = tile[kk + j][n];
    *(bf16x8*)(out + (size_t)(n0 + n) * K + k0 + kk) = o;
  }
}

// ---------------- grouped GEMM: 256x256 tile, BK=64, 8-phase schedule -------
// T2+T3+T4+T5 per m201/m248. LDS = As+Bs = EXACTLY 128 KB (matches the proven
// template footprint; round-3's +2.25 KB sSlot/sW removed -> slot/weight read
// straight from lists/top_w, L2-resident). K-halves (A/B x kh0/kh1 x 2buf):
// consumption is phase-partitioned along K so staging a half is WAR-safe one
// phase after its last read. Phase = (mi_half, ksub) quadrant:
// 8 ds_read_b128 -> stage 1 half (2 glds16) -> barrier -> lgkmcnt(0) ->
// setprio(1) 16 MFMA setprio(0) -> barrier. vmcnt(8)+barrier before every
// even phase pair. Ledger (per-wave FIFO): iter I wait1..4 retire tile2I.kh0,
// tile2I.kh1, tile(2I+1).kh0, tile(2I+1).kh1 -- each exactly before its
// consuming phases; never 0 until tail (8,8,4,0). vmcnt fused with s_barrier
// => all waves' stages landed (cross-wave RAW closed).
// Stage map per iter (tiles t=2I,t+1): p0 Akh1(t+1), p1 Bkh1(t+1),
// p2 Akh0(t+2), p3 Bkh0(t+2), p4 Akh1(t+2), p5 Bkh1(t+2), p6 Akh0(t+3),
// p7 Bkh0(t+3).  512 thr = 8 waves (2M x 4N), wave tile 128x64, acc[8][4].
// L1: A = xb (row=slot>>1), out = silu -> bf16 h[slot][NDIM]
// L2: A = h (row=slot),     out = atomicAdd(d_out[token][col], w*acc) fp32
template <int KDIM, int NDIM, bool L1>
__global__ __launch_bounds__(512, 2) void moe_gemm_k(
    const short* __restrict__ A, const short* __restrict__ Bt,
    void* __restrict__ outp, const int* __restrict__ cnt,
    const int* __restrict__ lists, const float* __restrict__ top_w) {
  constexpr int NB = NDIM / 256;
  constexpr int MB = NTOK / 256;
  constexpr int NWG = NB * MB * NEXP;   // divisible by 8
  int id = blockIdx.x;
  id = (id & 7) * (NWG >> 3) + (id >> 3);   // XCD chunk swizzle (bijective)
  int n = id % NB;
  int rem = id / NB;
  int m = rem % MB;
  int e = rem / MB;

  int ce = cnt[e];
  int m0 = m * 256;
  if (m0 >= ce) return;
  int n0 = n * 256;
  const int* list = lists + e * NTOK;
  const short* B = Bt + (size_t)e * (size_t)NDIM * KDIM;

  __shared__ short As[2 * 2 * 256 * 32];  // [buf][kh][row][32k] = 64 KB
  __shared__ short Bs[2 * 2 * 256 * 32];  // 64 KB   (total exactly 128 KB)

  int tid = threadIdx.x;

  // stage mapping: thread covers rows R1=tid>>2, R2=R1+128, stored chunk tid&3
  // logical chunk q = (tid&3) ^ ((R>>1)&3); same q for R1,R2 (delta 128)
  int R1 = tid >> 2;
  int R2 = R1 + 128;
  int q  = ((tid & 3) ^ ((tid >> 3) & 3)) * 8;
  int idx1 = m0 + R1; if (idx1 >= ce) idx1 = ce - 1;
  int idx2 = m0 + R2; if (idx2 >= ce) idx2 = ce - 1;
  int s1 = list[idx1], s2 = list[idx2];
  int ar1 = L1 ? (s1 >> 1) : s1;
  int ar2 = L1 ? (s2 >> 1) : s2;
  const short* gA1 = A + (size_t)ar1 * KDIM + q;
  const short* gA2 = A + (size_t)ar2 * KDIM + q;
  const short* gB1 = B + (size_t)(n0 + R1) * KDIM + q;
  const short* gB2 = B + (size_t)(n0 + R2) * KDIM + q;

  int lane = tid & 63, wave = tid >> 6;
  int wm = wave & 1, wn = wave >> 1;       // 2M x 4N waves
  int lr = lane & 15, quad = lane >> 4;
  // read swizzle: cs = quad ^ ((R>>1)&3) = quad ^ ((lr>>1)&3) (row bases %16==0)
  int swz = (quad ^ ((lr >> 1) & 3)) * 8;
  int aoff[8], boff[4];
#pragma unroll
  for (int mi = 0; mi < 8; mi++)
    aoff[mi] = (wm * 128 + mi * 16 + lr) * 32 + swz;
#pragma unroll
  for (int ni = 0; ni < 4; ni++)
    boff[ni] = (wn * 64 + ni * 16 + lr) * 32 + swz;

  f32x4 acc[8][4] = {};

#define STAGE_A(BUF, KS, KO) do {                                   \
    glds16(gA1 + (KO), As + (BUF) * 16384 + (KS) * 8192 + tid * 8); \
    glds16(gA2 + (KO), As + (BUF) * 16384 + (KS) * 8192 + 4096 + tid * 8); \
  } while (0)
#define STAGE_B(BUF, KS, KO) do {                                   \
    glds16(gB1 + (KO), Bs + (BUF) * 16384 + (KS) * 8192 + tid * 8); \
    glds16(gB2 + (KO), Bs + (BUF) * 16384 + (KS) * 8192 + 4096 + tid * 8); \
  } while (0)

#define PHASE(BUF, KS, MH, ...) do {                                          \
    const short* aP = As + (BUF) * 16384 + (KS) * 8192;                       \
    const short* bP = Bs + (BUF) * 16384 + (KS) * 8192;                       \
    bf16x8 af[4], bg[4];                                                      \
    _Pragma("unroll")                                                         \
    for (int u = 0; u < 4; u++) af[u] = *(const bf16x8*)(aP + aoff[(MH) * 4 + u]); \
    _Pragma("unroll")                                                         \
    for (int v = 0; v < 4; v++) bg[v] = *(const bf16x8*)(bP + boff[v]);       \
    __VA_ARGS__;                                                              \
    asm volatile("s_barrier" ::: "memory");                                   \
    asm volatile("s_waitcnt lgkmcnt(0)" ::: "memory");                        \
    __builtin_amdgcn_s_setprio(1);                                            \
    _Pragma("unroll")                                                         \
    for (int u = 0; u < 4; u++)                                               \
      _Pragma("unroll")                                                       \
      for (int v = 0; v < 4; v++)                                             \
        acc[(MH) * 4 + u][v] = __builtin_amdgcn_mfma_f32_16x16x32_bf16(       \
            af[u], bg[v], acc[(MH) * 4 + u][v], 0, 0, 0);                     \
    __builtin_amdgcn_s_setprio(0);                                            \
    asm volatile("s_barrier" ::: "memory");                                   \
  } while (0)

  // prologue: 6 halves in consumption order (12 vmcnt increments)
  STAGE_A(0, 0, 0);    // Akh0(0)
  STAGE_B(0, 0, 0);    // Bkh0(0)
  STAGE_A(0, 1, 32);   // Akh1(0)
  STAGE_B(0, 1, 32);   // Bkh1(0)
  STAGE_A(1, 0, 64);   // Akh0(1)
  STAGE_B(1, 0, 64);   // Bkh0(1)

  constexpr int NT = KDIM / 64;     // K-tiles: 16 (L1) or 64 (L2)
  constexpr int NITER = NT / 2;     // 8 or 32
#pragma unroll 1
  for (int I = 0; I < NITER; I++) {
    int koA = I * 128;              // tile t = 2I base k-offset (shorts)
    bool more = (I + 1 < NITER);
    asm volatile("s_waitcnt vmcnt(8)\ns_barrier" ::: "memory");
    PHASE(0, 0, 0, { STAGE_A(1, 1, koA + 96); });          // p0
    PHASE(0, 0, 1, { STAGE_B(1, 1, koA + 96); });          // p1
    asm volatile("s_waitcnt vmcnt(8)\ns_barrier" ::: "memory");
    PHASE(0, 1, 0, { if (more) STAGE_A(0, 0, koA + 128); });  // p2
    PHASE(0, 1, 1, { if (more) STAGE_B(0, 0, koA + 128); });  // p3
    if (more) asm volatile("s_waitcnt vmcnt(8)\ns_barrier" ::: "memory");
    else      asm volatile("s_waitcnt vmcnt(4)\ns_barrier" ::: "memory");
    PHASE(1, 0, 0, { if (more) STAGE_A(0, 1, koA + 160); });  // p4
    PHASE(1, 0, 1, { if (more) STAGE_B(0, 1, koA + 160); });  // p5
    if (more) asm volatile("s_waitcnt vmcnt(8)\ns_barrier" ::: "memory");
    else      asm volatile("s_waitcnt vmcnt(0)\ns_barrier" ::: "memory");
    PHASE(1, 1, 0, { if (more) STAGE_A(1, 0, koA + 192); });  // p6
    PHASE(1, 1, 1, { if (more) STAGE_B(1, 0, koA + 192); });  // p7
  }
#undef PHASE
#undef STAGE_A
#undef STAGE_B

  // epilogue: C/D layout col = lane&15, row = quad*4 + reg  [m89/m91]
  int ncol0 = n0 + wn * 64 + lr;
#pragma unroll
  for (int mi = 0; mi < 8; mi++) {
#pragma unroll
    for (int rg = 0; rg < 4; rg++) {
      int r = wm * 128 + mi * 16 + quad * 4 + rg;
      int gm = m0 + r;
      if (gm < ce) {
        int slot = list[gm];
        float w = L1 ? 0.f : top_w[slot];
#pragma unroll
        for (int ni = 0; ni < 4; ni++) {
          float v = acc[mi][ni][rg];
          int col = ncol0 + ni * 16;
          if (L1) {
            float sv = v / (1.f + expf(-v));   // silu
            ((short*)outp)[(size_t)slot * NDIM + col] = f2bf(sv);
          } else {
            // fp32 accumulate straight into d_out; guard prevents dup adds
            atomicAdd((float*)outp + (size_t)(slot >> 1) * NDIM + col, v * w);
          }
        }
      }
    }
  }
}

extern "C" void kernel_launch(void* const* d_in, const int* in_sizes, int n_in,
                              void* d_out, int out_size, void* d_ws, size_t ws_size,
                              hipStream_t stream) {
  const float* x  = (const float*)d_in[0];   // [8192,1024] fp32
  const float* rw = (const float*)d_in[1];   // [8,1024]    fp32
  const float* w1 = (const float*)d_in[2];   // [8,1024,4096] fp32
  const float* w2 = (const float*)d_in[3];   // [8,4096,1024] fp32
  float* out = (float*)d_out;                // [8192*1024] fp32 ++ aux scalar

  char* ws = (char*)d_ws;
  size_t off = 0;
  auto alloc = [&](size_t b) { void* p = ws + off; off += (b + 255) & ~(size_t)255; return p; };
  short* wt    = (short*)alloc((size_t)NEXP * HID * INTER * 2);  //  64 MB shared: w1t then w2t
  short* h     = (short*)alloc((size_t)NSLOT * INTER * 2);       // 128 MB [slot][INTER]
  short* xb    = (short*)alloc((size_t)NTOK * HID * 2);          //  16 MB bf16 x
  int*   tidx  = (int*)alloc(NSLOT * 4);
  float* tw    = (float*)alloc(NSLOT * 4);
  int*   lists = (int*)alloc(NEXP * NTOK * 4);
  int*   cnt   = (int*)alloc(256);           // cnt[8] | probsum[8] | cnt1[8]
  float* probsum = (float*)(cnt + 8);
  float* cnt1    = (float*)(cnt + 16);

  hipMemsetAsync(cnt, 0, 256, stream);
  hipMemsetAsync(out, 0, (size_t)out_size * 4, stream);  // GEMM2 accumulates into it

  castx_k<<<(NTOK * HID / 4) / 256, 256, 0, stream>>>(x, xb);
  router_k<<<NTOK / 16, 256, 0, stream>>>(x, rw, tidx, tw, probsum, cnt1);
  aux_k<<<1, 64, 0, stream>>>(probsum, cnt1, out + (size_t)NTOK * HID);
  lists_k<<<NSLOT / 256, 256, 0, stream>>>(tidx, cnt, lists);

  // layer 1: transpose+cast w1 -> wt, grouped GEMM -> h (silu, bf16)
  transpose_k<<<dim3(INTER / 64, HID / 64, NEXP), 256, 0, stream>>>(w1, wt, HID, INTER);
  moe_gemm_k<HID, INTER, true>
      <<<(INTER / 256) * (NTOK / 256) * NEXP, 512, 0, stream>>>(
          xb, wt, h, cnt, lists, tw);

  // layer 2: transpose+cast w2 -> wt (reuse), grouped GEMM -> out (fp32 atomic)
  transpose_k<<<dim3(HID / 64, INTER / 64, NEXP), 256, 0, stream>>>(w2, wt, INTER, HID);
  moe_gemm_k<INTER, HID, false>
      <<<(HID / 256) * (NTOK / 256) * NEXP, 512, 0, stream>>>(
          h, wt, out, cnt, lists, tw);
}

// Round 9
// 841.360 us; speedup vs baseline: 1.1087x; 1.1087x over previous
//
#include <hip/hip_runtime.h>
#include <hip/hip_bf16.h>
#include <stdint.h>

#define NTOK  8192
#define HID   1024
#define INTER 4096
#define NEXP  8
#define NSLOT (NTOK * 2)

typedef __attribute__((ext_vector_type(4))) float f32x4;
typedef __attribute__((ext_vector_type(8))) short bf16x8;
typedef __attribute__((ext_vector_type(4))) short bf16x4;

__device__ __forceinline__ short f2bf(float f) {
  union { float f; uint32_t u; } v; v.f = f;
  uint32_t u = v.u;
  u += 0x7FFFu + ((u >> 16) & 1u);   // RNE
  return (short)(u >> 16);
}

// async global->LDS, 16B per lane; HW dest = wave-uniform base + lane*16
__device__ __forceinline__ void glds16(const short* g, short* l) {
  __builtin_amdgcn_global_load_lds(
      (const __attribute__((address_space(1))) void*)g,
      (__attribute__((address_space(3))) void*)l, 16, 0, 0);
}

// ---------------- router: 16 tokens/block, block-reduced atomics ------------
// Also fused: x fp32 -> bf16 cast (router already streams all of x; write the
// bf16 row inline -> saves a separate 32 MB read + one launch).
__global__ __launch_bounds__(256) void router_k(
    const float* __restrict__ x, const float* __restrict__ rw,
    short* __restrict__ xb,
    int* __restrict__ top_idx, float* __restrict__ top_w,
    float* __restrict__ probsum, float* __restrict__ cnt1) {
  __shared__ float lrw[NEXP * HID];       // 32 KB
  __shared__ float red[4][2 * NEXP];      // per-wave partials
  int tid = threadIdx.x;
  for (int i = tid * 4; i < NEXP * HID; i += 1024)
    *(f32x4*)(lrw + i) = *(const f32x4*)(rw + i);
  __syncthreads();
  int lane = tid & 63;
  int wv = tid >> 6;
  float pacc[NEXP], cacc[NEXP];
#pragma unroll
  for (int e = 0; e < NEXP; e++) { pacc[e] = 0.f; cacc[e] = 0.f; }
#pragma unroll
  for (int it = 0; it < 4; it++) {
    int t = blockIdx.x * 16 + it * 4 + wv;
    const float* xr = x + (size_t)t * HID;
    short* xbr = xb + (size_t)t * HID;
    float acc[NEXP];
#pragma unroll
    for (int e = 0; e < NEXP; e++) acc[e] = 0.f;
#pragma unroll
    for (int k4 = 0; k4 < 4; k4++) {
      int k = k4 * 256 + lane * 4;
      f32x4 xv = *(const f32x4*)(xr + k);
      bf16x4 o = { f2bf(xv.x), f2bf(xv.y), f2bf(xv.z), f2bf(xv.w) };
      *(bf16x4*)(xbr + k) = o;
#pragma unroll
      for (int e = 0; e < NEXP; e++) {
        f32x4 rv = *(const f32x4*)(lrw + e * HID + k);
        acc[e] += xv.x * rv.x + xv.y * rv.y + xv.z * rv.z + xv.w * rv.w;
      }
    }
#pragma unroll
    for (int e = 0; e < NEXP; e++) {
#pragma unroll
      for (int off = 32; off > 0; off >>= 1)
        acc[e] += __shfl_xor(acc[e], off);
    }
    float mx = acc[0];
#pragma unroll
    for (int e = 1; e < NEXP; e++) mx = fmaxf(mx, acc[e]);
    float p[NEXP], s = 0.f;
#pragma unroll
    for (int e = 0; e < NEXP; e++) { p[e] = expf(acc[e] - mx); s += p[e]; }
    float inv = 1.f / s;
    float p1 = -1.f, p2 = -1.f; int i1 = 0, i2 = 0;
#pragma unroll
    for (int e = 0; e < NEXP; e++) {
      float pe = p[e] * inv;
      p[e] = pe;
      if (pe > p1)      { p2 = p1; i2 = i1; p1 = pe; i1 = e; }
      else if (pe > p2) { p2 = pe; i2 = e; }
    }
    if (lane == 0) {
      float rs = 1.f / (p1 + p2);
      top_idx[t * 2] = i1; top_idx[t * 2 + 1] = i2;
      top_w[t * 2] = p1 * rs; top_w[t * 2 + 1] = p2 * rs;
#pragma unroll
      for (int e = 0; e < NEXP; e++) {
        pacc[e] += p[e];
        cacc[e] += (i1 == e) ? 1.f : 0.f;
      }
    }
  }
  if (lane == 0) {
#pragma unroll
    for (int e = 0; e < NEXP; e++) {
      red[wv][e] = pacc[e];
      red[wv][NEXP + e] = cacc[e];
    }
  }
  __syncthreads();
  if (tid < NEXP) {
    float s = 0.f, c = 0.f;
#pragma unroll
    for (int w = 0; w < 4; w++) { s += red[w][tid]; c += red[w][NEXP + tid]; }
    atomicAdd(&probsum[tid], s);
    atomicAdd(&cnt1[tid], c);
  }
}

__global__ void aux_k(const float* probsum, const float* cnt1, float* out_aux) {
  if (threadIdx.x == 0 && blockIdx.x == 0) {
    float s = 0.f;
    for (int e = 0; e < NEXP; e++) s += cnt1[e] * probsum[e];
    out_aux[0] = s * (float)NEXP / ((float)NTOK * (float)NTOK);
  }
}

__global__ void lists_k(const int* __restrict__ top_idx, int* __restrict__ cnt,
                        int* __restrict__ lists) {
  int i = blockIdx.x * 256 + threadIdx.x;
  if (i < NSLOT) {
    int e = top_idx[i];
    int pos = atomicAdd(cnt + e, 1);
    lists[e * NTOK + pos] = i;   // slot id = token*2 + k
  }
}

// -------- transpose + downcast: fp32 [K][N] -> bf16 [N][K], per expert ------
__global__ __launch_bounds__(256) void transpose_k(
    const float* __restrict__ in, short* __restrict__ out, int K, int N) {
  __shared__ short tile[64][72];   // +8 pad
  int e = blockIdx.z;
  in  += (size_t)e * K * N;
  out += (size_t)e * K * N;
  int n0 = blockIdx.x * 64, k0 = blockIdx.y * 64;
  int tid = threadIdx.x;
#pragma unroll
  for (int i = 0; i < 4; i++) {
    int k = (tid >> 4) + i * 16;
    int c = (tid & 15) * 4;
    f32x4 v = *(const f32x4*)(in + (size_t)(k0 + k) * N + n0 + c);
    tile[k][c] = f2bf(v.x); tile[k][c + 1] = f2bf(v.y);
    tile[k][c + 2] = f2bf(v.z); tile[k][c + 3] = f2bf(v.w);
  }
  __syncthreads();
#pragma unroll
  for (int i = 0; i < 2; i++) {
    int cid = tid + i * 256;
    int n = cid >> 3, kk = (cid & 7) * 8;
    bf16x8 o;
#pragma unroll
    for (int j = 0; j < 8; j++) o[j] = tile[kk + j][n];
    *(bf16x8*)(out + (size_t)(n0 + n) * K + k0 + kk) = o;
  }
}

// ---------------- grouped GEMM: 128x128 tile, BK=32, 16x16x32 bf16 MFMA ------
// Verified round-1 structure (the best-measured config): 2-phase double-
// buffered pipeline, ONE __syncthreads per K-step (implicit vmcnt/lgkm drain
// handles both the buf1-ready RAW and the buf0-overwrite WAR). Bijective XCD
// chunk swizzle with n innermost for L2 panel sharing (FETCH showed 98% of
// staging hits L2/L3). __launch_bounds__(256, 4) pins 4 blocks/CU (VGPR<=128;
// measured 84) so the barrier-drain stall of one block hides under the other
// three blocks' MFMA (m114 cross-block overlap).
// Raw-barrier counted-vmcnt variants (r5/r6) could not be measured (infra);
// __syncthreads-only sync here.
// L1: A = xb (row=slot>>1), out = silu -> bf16 h[slot][Ndim]
// L2: A = h (row=slot),     out = atomicAdd(d_out[token][col], w*acc) fp32
template <int KDIM, int NDIM, bool L1>
__global__ __launch_bounds__(256, 4) void moe_gemm_k(
    const short* __restrict__ A, const short* __restrict__ Bt,
    void* __restrict__ outp, const int* __restrict__ cnt,
    const int* __restrict__ lists, const float* __restrict__ top_w) {
  constexpr int NB = NDIM / 128;
  constexpr int MB = NTOK / 128;
  constexpr int NWG = NB * MB * NEXP;   // divisible by 8
  int id = blockIdx.x;
  id = (id & 7) * (NWG >> 3) + (id >> 3);   // XCD chunk swizzle (bijective)
  int n = id % NB;
  int rem = id / NB;
  int m = rem % MB;
  int e = rem / MB;

  int ce = cnt[e];
  int m0 = m * 128;
  if (m0 >= ce) return;
  int n0 = n * 128;
  const int* list = lists + e * NTOK;
  const short* B = Bt + (size_t)e * (size_t)NDIM * KDIM;

  __shared__ short As[2][128 * 32];  // [r][k] 64B rows, XOR-swizzled 16B chunks
  __shared__ short Bs[2][128 * 32];  // [n][k] same layout
  __shared__ int   sSlot[128];
  __shared__ float sW[128];

  int tid = threadIdx.x;
  if (tid < 128) {
    int idx = m0 + tid;
    if (idx >= ce) idx = ce - 1;
    int slot = list[idx];
    sSlot[tid] = slot;
    sW[tid] = L1 ? 0.f : top_w[slot];
  }
  __syncthreads();

  // staging: thread covers (row r, stored chunk cs); loads logical chunk
  // q = cs ^ ((r>>1)&3)  -> conflict-free b128 frag reads (measured 0)
  int r1 = tid >> 2, cs = tid & 3;
  int r2 = r1 + 64;
  int q1 = (cs ^ ((r1 >> 1) & 3)) * 8;
  int q2 = (cs ^ ((r2 >> 1) & 3)) * 8;
  int ar1 = L1 ? (sSlot[r1] >> 1) : sSlot[r1];
  int ar2 = L1 ? (sSlot[r2] >> 1) : sSlot[r2];
  const short* gA1 = A + (size_t)ar1 * KDIM + q1;
  const short* gA2 = A + (size_t)ar2 * KDIM + q2;
  const short* gB1 = B + (size_t)(n0 + r1) * KDIM + q1;
  const short* gB2 = B + (size_t)(n0 + r2) * KDIM + q2;

  int lane = tid & 63, wave = tid >> 6;
  int wm = wave & 1, wn = wave >> 1;
  int lr = lane & 15, quad = lane >> 4;
  int aoff[4], boff[4];
#pragma unroll
  for (int mi = 0; mi < 4; mi++) {
    int r = wm * 64 + mi * 16 + lr;
    aoff[mi] = r * 32 + (quad ^ ((r >> 1) & 3)) * 8;
  }
#pragma unroll
  for (int ni = 0; ni < 4; ni++) {
    int nn = wn * 64 + ni * 16 + lr;
    boff[ni] = nn * 32 + (quad ^ ((nn >> 1) & 3)) * 8;
  }

  f32x4 acc[4][4] = {};

#define STAGE(buf, ko)                                  \
  do {                                                  \
    glds16(gA1 + (ko), As[buf] + tid * 8);              \
    glds16(gA2 + (ko), As[buf] + 2048 + tid * 8);       \
    glds16(gB1 + (ko), Bs[buf] + tid * 8);              \
    glds16(gB2 + (ko), Bs[buf] + 2048 + tid * 8);       \
  } while (0)

#define COMPUTE(buf)                                                          \
  do {                                                                        \
    bf16x8 af[4], bfg[4];                                                     \
    _Pragma("unroll")                                                         \
    for (int mi = 0; mi < 4; mi++) af[mi] = *(const bf16x8*)(As[buf] + aoff[mi]); \
    _Pragma("unroll")                                                         \
    for (int ni = 0; ni < 4; ni++) bfg[ni] = *(const bf16x8*)(Bs[buf] + boff[ni]); \
    _Pragma("unroll")                                                         \
    for (int mi = 0; mi < 4; mi++)                                            \
      _Pragma("unroll")                                                       \
      for (int ni = 0; ni < 4; ni++)                                          \
        acc[mi][ni] = __builtin_amdgcn_mfma_f32_16x16x32_bf16(af[mi], bfg[ni], acc[mi][ni], 0, 0, 0); \
  } while (0)

  constexpr int NK = KDIM / 32;   // 32 (L1) or 128 (L2), always even
  STAGE(0, 0);
  __syncthreads();                // drains prologue stage
  for (int kt = 0; kt < NK; kt += 2) {
    STAGE(1, (kt + 1) * 32);      // prefetch next tile into buf1
    COMPUTE(0);
    __syncthreads();              // vmcnt(0)+lgkmcnt(0) drain: buf1 ready, buf0 free
    if (kt + 2 < NK) STAGE(0, (kt + 2) * 32);
    COMPUTE(1);
    __syncthreads();
  }
#undef STAGE
#undef COMPUTE

  // epilogue: C/D layout col = lane&15, row = quad*4 + reg  [m89/m91]
  int ncol0 = n0 + wn * 64 + lr;
#pragma unroll
  for (int mi = 0; mi < 4; mi++) {
#pragma unroll
    for (int rg = 0; rg < 4; rg++) {
      int r = wm * 64 + mi * 16 + quad * 4 + rg;
      int gm = m0 + r;
      if (gm < ce) {
        int slot = sSlot[r];
#pragma unroll
        for (int ni = 0; ni < 4; ni++) {
          float v = acc[mi][ni][rg];
          int col = ncol0 + ni * 16;
          if (L1) {
            float sv = v / (1.f + expf(-v));   // silu
            ((short*)outp)[(size_t)slot * NDIM + col] = f2bf(sv);
          } else {
            // fp32 accumulate straight into d_out; guard prevents dup adds
            atomicAdd((float*)outp + (size_t)(slot >> 1) * NDIM + col, v * sW[r]);
          }
        }
      }
    }
  }
}

extern "C" void kernel_launch(void* const* d_in, const int* in_sizes, int n_in,
                              void* d_out, int out_size, void* d_ws, size_t ws_size,
                              hipStream_t stream) {
  const float* x  = (const float*)d_in[0];   // [8192,1024] fp32
  const float* rw = (const float*)d_in[1];   // [8,1024]    fp32
  const float* w1 = (const float*)d_in[2];   // [8,1024,4096] fp32
  const float* w2 = (const float*)d_in[3];   // [8,4096,1024] fp32
  float* out = (float*)d_out;                // [8192*1024] fp32 ++ aux scalar

  char* ws = (char*)d_ws;
  size_t off = 0;
  auto alloc = [&](size_t b) { void* p = ws + off; off += (b + 255) & ~(size_t)255; return p; };
  short* wt    = (short*)alloc((size_t)NEXP * HID * INTER * 2);  //  64 MB shared: w1t then w2t
  short* h     = (short*)alloc((size_t)NSLOT * INTER * 2);       // 128 MB [slot][INTER]
  short* xb    = (short*)alloc((size_t)NTOK * HID * 2);          //  16 MB bf16 x
  int*   tidx  = (int*)alloc(NSLOT * 4);
  float* tw    = (float*)alloc(NSLOT * 4);
  int*   lists = (int*)alloc(NEXP * NTOK * 4);
  int*   cnt   = (int*)alloc(256);           // cnt[8] | probsum[8] | cnt1[8]
  float* probsum = (float*)(cnt + 8);
  float* cnt1    = (float*)(cnt + 16);

  hipMemsetAsync(cnt, 0, 256, stream);
  hipMemsetAsync(out, 0, (size_t)out_size * 4, stream);  // GEMM2 accumulates into it

  router_k<<<NTOK / 16, 256, 0, stream>>>(x, rw, xb, tidx, tw, probsum, cnt1);
  aux_k<<<1, 64, 0, stream>>>(probsum, cnt1, out + (size_t)NTOK * HID);
  lists_k<<<NSLOT / 256, 256, 0, stream>>>(tidx, cnt, lists);

  // layer 1: transpose+cast w1 -> wt, grouped GEMM -> h (silu, bf16)
  transpose_k<<<dim3(INTER / 64, HID / 64, NEXP), 256, 0, stream>>>(w1, wt, HID, INTER);
  moe_gemm_k<HID, INTER, true>
      <<<(INTER / 128) * (NTOK / 128) * NEXP, 256, 0, stream>>>(
          xb, wt, h, cnt, lists, tw);

  // layer 2: transpose+cast w2 -> wt (reuse), grouped GEMM -> out (fp32 atomic)
  transpose_k<<<dim3(HID / 64, INTER / 64, NEXP), 256, 0, stream>>>(w2, wt, INTER, HID);
  moe_gemm_k<INTER, HID, false>
      <<<(HID / 128) * (NTOK / 128) * NEXP, 256, 0, stream>>>(
          h, wt, out, cnt, lists, tw);
}